// Round 11
// baseline (26.445 us; speedup 1.0000x reference)
//
#include <hip/hip_runtime.h>
#include <hip/hip_bf16.h>
#include <math.h>

// y[n,o] = min_i (x[n,i] + w[o,i]) + bias[o]
// x: (32768,128) f32, w: (128,128) f32, bias: (128,) f32, out: (32768,128) f32
//
// Round-10 f16 single-phase structure at FULL occupancy: 512-thread blocks
// (8 waves), 4x2 thread tile, launch_bounds(512,8) -> VGPR<=64 -> 8 waves/SIMD
// -> 32 waves/CU (4 blocks x 34.8 KB LDS). The round-10 evidence: halving
// VALU+LDS work gained 5% -> latency-stall-bound at 4 waves/SIMD; this doubles
// the TLP with the VALU floor unchanged (~6.8 us).
// All LDS reads share ONE vaddr per operand (16-bit imm offsets <= 13 KB).

typedef __fp16 h2 __attribute__((ext_vector_type(2)));
typedef __fp16 h4 __attribute__((ext_vector_type(4)));
typedef __fp16 h8 __attribute__((ext_vector_type(8)));

constexpr int K     = 128;
constexpr int BM    = 64;
constexpr int BN    = 64;
constexpr int LDRH2 = 68;        // row stride in h2 units (272 B, 16B-aligned)

__global__ __launch_bounds__(512, 8)
void minplus_kernel(const float* __restrict__ x,
                    const float* __restrict__ w,
                    const float* __restrict__ bias,
                    float* __restrict__ out)
{
    __shared__ h2 lds[(BM + BN) * LDRH2];    // 34,816 B -> 4 blocks/CU
    h2* xs = lds;
    h2* ws = lds + BM * LDRH2;

    const int tid = threadIdx.x;
    const int rt  = blockIdx.x & 511;        // ct in HIGH bit: both col-halves of
    const int ct  = blockIdx.x >> 9;         // a row-tile share an XCD L2

    const float* xsrc = x + (size_t)rt * BM * K;
    const float* wsrc = w + (size_t)ct * BN * K;

    // ---- stage both 64x128 tiles, f32 -> f16 (cvt_pkrtz), coalesced ----
    #pragma unroll
    for (int p = 0; p < 4; ++p) {
        int c   = p * 512 + tid;             // float4-chunk id, 0..2047
        int row = c >> 5;                    // 0..63
        int q   = c & 31;                    // float4 chunk within 128-f32 row
        float4 xv = *(const float4*)(xsrc + row * K + q * 4);
        float4 wv = *(const float4*)(wsrc + row * K + q * 4);
        h2 xa = __builtin_amdgcn_cvt_pkrtz(xv.x, xv.y);
        h2 xb = __builtin_amdgcn_cvt_pkrtz(xv.z, xv.w);
        h2 wa = __builtin_amdgcn_cvt_pkrtz(wv.x, wv.y);
        h2 wb = __builtin_amdgcn_cvt_pkrtz(wv.z, wv.w);
        h4 xh = __builtin_shufflevector(xa, xb, 0, 1, 2, 3);
        h4 wh = __builtin_shufflevector(wa, wb, 0, 1, 2, 3);
        *(h4*)(xs + row * LDRH2 + q * 2) = xh;   // 8B ds_write_b64
        *(h4*)(ws + row * LDRH2 + q * 2) = wh;
    }
    __syncthreads();                         // the ONLY barrier

    const int ty = tid >> 5;                 // 0..15 : rows ty + 16m (m=0..3)
    const int tx = tid & 31;                 // 0..31 : cols tx, tx+32
    const h2* xbp = xs + ty * LDRH2;         // one vaddr; imm offsets m*4352+kc*16
    const h2* wbp = ws + tx * LDRH2;         // one vaddr; imm offsets {0,8704}+kc*16

    h2 hbig;
    hbig.x = (__fp16)65504.0f;
    hbig.y = (__fp16)65504.0f;
    h2 acc[4][2];
    #pragma unroll
    for (int m = 0; m < 4; ++m) {
        acc[m][0] = hbig;
        acc[m][1] = hbig;
    }

    // ---- 16 chunks of 8 k-elems; per chunk: 6 ds_read_b128 + 64 pk-VALU ----
    #pragma unroll 4
    for (int kc = 0; kc < 16; ++kc) {
        h8 xv0 = *(const h8*)(xbp + 0 * 16 * LDRH2 + kc * 4);
        h8 xv1 = *(const h8*)(xbp + 1 * 16 * LDRH2 + kc * 4);
        h8 xv2 = *(const h8*)(xbp + 2 * 16 * LDRH2 + kc * 4);
        h8 xv3 = *(const h8*)(xbp + 3 * 16 * LDRH2 + kc * 4);
        h8 wv0 = *(const h8*)(wbp + kc * 4);
        h8 wv1 = *(const h8*)(wbp + 32 * LDRH2 + kc * 4);

#define UPD(m, n, XV, WV)                                                     \
        {                                                                     \
            h8 t  = XV + WV;                 /* 4x v_pk_add_f16 */            \
            h2 t0 = __builtin_shufflevector(t, t, 0, 1);                      \
            h2 t1 = __builtin_shufflevector(t, t, 2, 3);                      \
            h2 t2 = __builtin_shufflevector(t, t, 4, 5);                      \
            h2 t3 = __builtin_shufflevector(t, t, 6, 7);                      \
            h2 u  = __builtin_elementwise_min(t0, t1);                        \
            h2 v  = __builtin_elementwise_min(t2, t3);                        \
            h2 uv = __builtin_elementwise_min(u, v);                          \
            acc[m][n] = __builtin_elementwise_min(acc[m][n], uv);             \
        }
        UPD(0, 0, xv0, wv0) UPD(0, 1, xv0, wv1)
        UPD(1, 0, xv1, wv0) UPD(1, 1, xv1, wv1)
        UPD(2, 0, xv2, wv0) UPD(2, 1, xv2, wv1)
        UPD(3, 0, xv3, wv0) UPD(3, 1, xv3, wv1)
#undef UPD
    }

    // ---- epilogue: f16 pair-reduce -> f32, + bias, coalesced store ----
    const int rowbase = rt * BM + ty;
    const int colbase = ct * BN + tx;
    const float b0 = bias[colbase];
    const float b1 = bias[colbase + 32];
    #pragma unroll
    for (int m = 0; m < 4; ++m) {
        float* orow = out + (size_t)(rowbase + 16 * m) * 128 + colbase;
        h2 a0 = acc[m][0];
        h2 a1 = acc[m][1];
        orow[0]  = fminf((float)a0.x, (float)a0.y) + b0;
        orow[32] = fminf((float)a1.x, (float)a1.y) + b1;
    }
}

extern "C" void kernel_launch(void* const* d_in, const int* in_sizes, int n_in,
                              void* d_out, int out_size, void* d_ws, size_t ws_size,
                              hipStream_t stream) {
    const float* x    = (const float*)d_in[0];
    const float* w    = (const float*)d_in[1];
    const float* bias = (const float*)d_in[2];
    float* out = (float*)d_out;

    int nrows  = in_sizes[0] / K;             // 32768
    int blocks = (nrows / BM) * (K / BN);     // 1024
    minplus_kernel<<<blocks, 512, 0, stream>>>(x, w, bias, out);
}